// Round 3
// baseline (3148.718 us; speedup 1.0000x reference)
//
#include <hip/hip_runtime.h>
#include <math.h>

#define Bn   256
#define Tn   128
#define HID  64
#define MCn  30

// ---------------------------------------------------------------------------
// fast transcendentals (v_exp_f32 / v_rcp_f32 based)
__device__ __forceinline__ float rcp_(float x) { return __builtin_amdgcn_rcpf(x); }
__device__ __forceinline__ float tanhf_(float x) {
    float xx = fminf(fmaxf(x, -9.0f), 9.0f);
    float e  = __expf(2.0f * xx);
    return (e - 1.0f) * rcp_(e + 1.0f);
}
__device__ __forceinline__ float sigmoidf_(float x) {
    return rcp_(1.0f + __expf(-x));
}
__device__ __forceinline__ float softplusf_(float z) {
    float e = __expf(-fabsf(z));
    return fmaxf(z, 0.0f) + __logf(1.0f + e);
}

// parw image layout (floats):
//   [0    .. 4096 )  w0sT[(l*64+jj)*32+kk] = fW0[l][32l+kk][jj]
//   [4096 ..12288 )  w1s = fW1 verbatim
//   [12288..20480 )  w2s[(l*64+k)*64+i] = fW2[l][k][act+(i&31)+64*(i>>5)]
//   [20480..20608 )  w0ts[l*64+jj] = fW0[l][64][jj]
//   [20608..20736 )  fb0
//   [20736..20864 )  fb1
//   [20864..20992 )  fb2c[l*64+i] = fb2[l][act+(i&31)+64*(i>>5)]
//   [20992..21056 )  ftwa[l*32+i] = ftw[l][act+i]        (scale t-weights)
//   [21056..21120 )  ftwb[l*32+i] = ftw[l][64+act+i]     (shift t-weights)
//   [21120..21184 )  Wi
//   [21184..21248 )  pad
#define PARW_FLOATS 21248

extern "C" __global__ __launch_bounds__(256)
void prep_kernel(const int* __restrict__ marks, const float* __restrict__ mask,
                 const float* __restrict__ emb, const float* __restrict__ fW0,
                 const float* __restrict__ fW1, const float* __restrict__ fW2,
                 const float* __restrict__ fb0, const float* __restrict__ fb1,
                 const float* __restrict__ fb2, const float* __restrict__ ftw,
                 const float* __restrict__ Wi, const float* __restrict__ W_ih,
                 const float* __restrict__ b_ih, const float* __restrict__ b_hh,
                 float* __restrict__ gc, float* __restrict__ parw,
                 float* __restrict__ invd)
{
    __shared__ float red[4];
    const int blk = blockIdx.x, tid = threadIdx.x;
    if (blk < Bn) {
        const int mark = marks[blk * Tn + 1];
        const float* er = emb + mark * HID;
        const float* wr = W_ih + tid * 65 + 1;
        float acc = b_ih[tid] + b_hh[tid];
        #pragma unroll
        for (int k = 0; k < HID; k++) acc += er[k] * wr[k];
        gc[blk * 256 + tid] = acc;
    } else if (blk == Bn) {
        float s = 0.f;
        for (int i = tid; i < Bn * Tn; i += 256) s += mask[i];
        #pragma unroll
        for (int off = 32; off >= 1; off >>= 1) s += __shfl_xor(s, off, 64);
        if ((tid & 63) == 0) red[tid >> 6] = s;
        __syncthreads();
        if (tid == 0) invd[0] = 1.0f / (red[0] + red[1] + red[2] + red[3]);
    } else if (blk == Bn + 1) {
        for (int i = tid; i < 4096; i += 256) {
            int kk = i & 31, jj = (i >> 5) & 63, l = i >> 11;
            parw[i] = fW0[(l * 65 + 32 * l + kk) * 64 + jj];
        }
    } else if (blk == Bn + 2) {
        for (int i = tid; i < 8192; i += 256) parw[4096 + i] = fW1[i];
    } else if (blk == Bn + 3) {
        for (int i = tid; i < 8192; i += 256) {
            int col = i & 63, k = (i >> 6) & 63, l = i >> 12;
            int act = 32 * (1 - l);
            parw[12288 + i] = fW2[(l * 64 + k) * 128 + act + (col & 31) + 64 * (col >> 5)];
        }
    } else {
        if (tid < 128) {
            int l = tid >> 6, jj = tid & 63;
            parw[20480 + tid] = fW0[(l * 65 + 64) * 64 + jj];
            parw[20608 + tid] = fb0[tid];
            parw[20736 + tid] = fb1[tid];
            int act = 32 * (1 - l), ii = jj;
            parw[20864 + tid] = fb2[l * 128 + act + (ii & 31) + 64 * (ii >> 5)];
        }
        if (tid < 64) {
            int l = tid >> 5, ii = tid & 31, act = 32 * (1 - l);
            parw[20992 + tid] = ftw[l * 128 + act + ii];
            parw[21056 + tid] = ftw[l * 128 + 64 + act + ii];
            parw[21120 + tid] = Wi[tid];
            parw[21184 + tid] = 0.f;
        }
    }
}

// ---------------------------------------------------------------------------
// Sequential kernel: one block (4 waves) per batch element. mv1/mv2 replicated
// per wave (register weights + private LDS broadcast buffers, no cross-wave
// sync); mv3 and LSTM split across the 4 waves with register weights. 3
// __syncthreads per step.
extern "C" __global__ __launch_bounds__(256, 1)
void seq_kernel(const float* __restrict__ times, const float* __restrict__ mask,
                const float* __restrict__ fW0, const float* __restrict__ fb0,
                const float* __restrict__ fW1, const float* __restrict__ fb1,
                const float* __restrict__ fb2, const float* __restrict__ ftw,
                const float* __restrict__ Wi, const float* __restrict__ bi,
                const float* __restrict__ W_ih, const float* __restrict__ W_hh,
                const float* __restrict__ gc, const float* __restrict__ parw,
                const float* __restrict__ invd,
                float* __restrict__ h_carry, float* __restrict__ out)
{
    const int tid = threadIdx.x;
    const int j = tid & 63;        // lane
    const int w = tid >> 6;        // wave 0..3
    const int b = blockIdx.x;
    const bool w0 = (w == 0);

    __shared__ __align__(16) float xl[4][64];
    __shared__ __align__(16) float al[4][64];
    __shared__ __align__(16) float al2[4][64];
    __shared__ float ssl[2][64];
    __shared__ float gl[256];

    // ---- per-lane register weights ----
    float w0c[2][32], w0tc[2], b0c[2], w1c[2][64], b1c[2];
    float w2c[2][16], b2c[2], ftsc[2], ftsh[2];
    const int o = w * 16 + (j & 15);   // mv3 output col owned by this lane
    const int p = j >> 4;              // mv3 k-quarter
    #pragma unroll
    for (int l = 0; l < 2; l++) {
        #pragma unroll
        for (int kk = 0; kk < 32; kk++)
            w0c[l][kk] = fW0[(l * 65 + 32 * l + kk) * 64 + j];
        w0tc[l] = fW0[(l * 65 + 64) * 64 + j];
        b0c[l]  = fb0[l * 64 + j];
        #pragma unroll
        for (int k = 0; k < 64; k++)
            w1c[l][k] = fW1[(l * 64 + k) * 64 + j];
        b1c[l] = fb1[l * 64 + j];
        #pragma unroll
        for (int kk = 0; kk < 16; kk++)
            w2c[l][kk] = parw[12288 + (l * 64 + p * 16 + kk) * 64 + o];
        const int act = 32 * (1 - l);
        b2c[l]  = fb2[l * 128 + act + (o & 31) + 64 * (o >> 5)];
        ftsc[l] = ftw[l * 128 + j];
        ftsh[l] = ftw[l * 128 + 64 + j];
    }
    float whc[64];                     // LSTM: lane (w,j) owns gate w*64+j
    {
        const float4* src = (const float4*)(W_hh + (w * 64 + j) * 64);
        #pragma unroll
        for (int k4 = 0; k4 < 16; k4++) {
            float4 v = src[k4];
            whc[4 * k4 + 0] = v.x; whc[4 * k4 + 1] = v.y;
            whc[4 * k4 + 2] = v.z; whc[4 * k4 + 3] = v.w;
        }
    }
    const float gcr  = gc[b * 256 + w * 64 + j];
    const float wih0 = W_ih[(w * 64 + j) * 65];
    const float wij  = Wi[j];
    const float bi0  = bi[0];
    const float idn  = invd[0];

    float h = 0.f, c = 0.f, nllacc = 0.f;
    float tb = times[b * Tn];
    float mk = mask[b * Tn];
    for (int t = 0; t < Tn; t++) {
        const int tn = (t < Tn - 1) ? t + 1 : t;
        const float tb_n = times[b * Tn + tn];       // prefetch
        const float mk_n = mask[b * Tn + tn];

        if (w0) h_carry[(b * Tn + t) * 64 + j] = h;
        float x = h;
        xl[w][j] = x;
        #pragma unroll
        for (int l = 0; l < 2; l++) {
            const int kb  = 32 * l;
            const int act = 32 * (1 - l);
            // mv1 (replicated): broadcast kept half of x, register weights
            float p0 = b0c[l] + tb * w0tc[l], p1 = 0.f, p2 = 0.f, p3 = 0.f;
            {
                const float4* xv4 = (const float4*)(&xl[w][kb]);
                #pragma unroll
                for (int k4 = 0; k4 < 8; k4++) {
                    float4 xv = xv4[k4];
                    p0 += xv.x * w0c[l][4 * k4 + 0];
                    p1 += xv.y * w0c[l][4 * k4 + 1];
                    p2 += xv.z * w0c[l][4 * k4 + 2];
                    p3 += xv.w * w0c[l][4 * k4 + 3];
                }
            }
            const float a1 = tanhf_((p0 + p1) + (p2 + p3));
            al[w][j] = a1;
            // mv2 (replicated)
            p0 = b1c[l]; p1 = p2 = p3 = 0.f;
            {
                const float4* av4 = (const float4*)(&al[w][0]);
                #pragma unroll
                for (int k4 = 0; k4 < 16; k4++) {
                    float4 av = av4[k4];
                    p0 += av.x * w1c[l][4 * k4 + 0];
                    p1 += av.y * w1c[l][4 * k4 + 1];
                    p2 += av.z * w1c[l][4 * k4 + 2];
                    p3 += av.w * w1c[l][4 * k4 + 3];
                }
            }
            const float a2 = tanhf_((p0 + p1) + (p2 + p3));
            al2[w][j] = a2;
            // mv3 (split): lane (w,j) = output o, k-quarter p
            float s0 = 0.f, s1 = 0.f, s2 = 0.f, s3 = 0.f;
            {
                const float4* av4 = (const float4*)(&al2[w][p * 16]);
                #pragma unroll
                for (int k4 = 0; k4 < 4; k4++) {
                    float4 av = av4[k4];
                    s0 += av.x * w2c[l][4 * k4 + 0];
                    s1 += av.y * w2c[l][4 * k4 + 1];
                    s2 += av.z * w2c[l][4 * k4 + 2];
                    s3 += av.w * w2c[l][4 * k4 + 3];
                }
            }
            float ss = (s0 + s1) + (s2 + s3);
            ss += __shfl_xor(ss, 16, 64);
            ss += __shfl_xor(ss, 32, 64);
            ss += b2c[l];
            if ((j & 48) == 0) ssl[l][w * 16 + j] = ss;   // j<16 lanes write
            __syncthreads();
            // coupling (replicated)
            const int idx = (j - act) & 31;
            const float scl = ssl[l][idx];
            const float shf = ssl[l][32 + idx];
            const float tsc = tanhf_(tb * ftsc[l]);
            const float tsh = tanhf_(tb * ftsh[l]);
            const float xa  = x * __expf(scl * tsc) + shf * tsh;
            const bool active = (l == 0) ? (j >= 32) : (j < 32);
            x = active ? xa : x;
            xl[w][j] = x;
        }
        // h2 = x
        if (w0) out[1 + (b * Tn + t) * 64 + j] = x;
        // nll (replicated butterfly; only wave 0 accumulates)
        float v = x * wij;
        #pragma unroll
        for (int off = 32; off >= 1; off >>= 1) v += __shfl_xor(v, off, 64);
        const float lam = softplusf_(v + bi0);
        if (w0) nllacc += -__logf(lam) * mk;
        // LSTM (split): lane (w,j) computes gate w*64+j
        float g0 = gcr + tb * wih0, g1 = 0.f, g2 = 0.f, g3 = 0.f;
        {
            const float4* hv4 = (const float4*)(&xl[w][0]);
            #pragma unroll
            for (int k4 = 0; k4 < 16; k4++) {
                float4 hv = hv4[k4];
                g0 += hv.x * whc[4 * k4 + 0];
                g1 += hv.y * whc[4 * k4 + 1];
                g2 += hv.z * whc[4 * k4 + 2];
                g3 += hv.w * whc[4 * k4 + 3];
            }
        }
        gl[w * 64 + j] = (g0 + g1) + (g2 + g3);
        __syncthreads();
        const float gi = gl[j], gf = gl[64 + j], gg = gl[128 + j], go = gl[192 + j];
        c = sigmoidf_(gf) * c + sigmoidf_(gi) * tanhf_(gg);
        h = sigmoidf_(go) * tanhf_(c);
        tb = tb_n; mk = mk_n;
    }
    if (tid == 0) atomicAdd(out, nllacc * idn);
}

// ---------------------------------------------------------------------------
// Parallel kernel: one thread = one (t,b,mc) sample. ALL in-loop operands are
// LDS-resident (activation columns + full weight image) so every wait is a
// fine-grained in-order DS wait; x[]/acc[] in registers, 1 block/CU, 512-VGPR
// budget (no spills).
extern "C" __global__ __launch_bounds__(256, 1)
void par_kernel(const float* __restrict__ times, const float* __restrict__ mask,
                const float* __restrict__ u, const float* __restrict__ bi,
                const float* __restrict__ invd, const float* __restrict__ parw,
                const float* __restrict__ h_carry, float* __restrict__ out)
{
    const int tid = threadIdx.x;
    extern __shared__ float lds[];
    float* as_ = lds;                  // [64][256] per-thread columns
    float* img = lds + 16384;          // parw image

    // stage the weight image (flat float4 copy)
    {
        const float4* src = (const float4*)parw;
        float4* dst = (float4*)img;
        for (int i = tid; i < PARW_FLOATS / 4; i += 256) dst[i] = src[i];
    }
    const float* w0sT = img;
    const float* w1s  = img + 4096;
    const float* w2s  = img + 12288;
    const float* w0ts = img + 20480;
    const float* fb0s = img + 20608;
    const float* fb1s = img + 20736;
    const float* fb2c = img + 20864;
    const float* ftwa = img + 20992;
    const float* ftwb = img + 21056;
    const float* wis  = img + 21120;

    const int s  = blockIdx.x * 256 + tid;
    const int mc = s % MCn;
    const int q  = s / MCn;
    const int b  = q & 255;
    const int t  = q >> 8;
    const float tb = times[b * Tn + t];
    const float ts = u[t * MCn + mc] * tb;
    const float scalef = tb * (1.0f / MCn) * invd[0] * mask[b * Tn + t];
    const float bi0 = bi[0];

    float x[64];
    {
        const float4* hrow = (const float4*)(h_carry + (b * Tn + t) * 64);
        #pragma unroll
        for (int k4 = 0; k4 < 16; k4++) {
            float4 v = hrow[k4];
            x[4 * k4 + 0] = v.x; x[4 * k4 + 1] = v.y;
            x[4 * k4 + 2] = v.z; x[4 * k4 + 3] = v.w;
        }
    }
    __syncthreads();

    #pragma unroll
    for (int l = 0; l < 2; l++) {
        const int kb  = 32 * l;
        const int act = 32 * (1 - l);
        // mv1: per-output dot, weights broadcast from LDS
        for (int jj = 0; jj < 64; jj++) {
            const float4* wr = (const float4*)(w0sT + (l * 64 + jj) * 32);
            float s0 = fb0s[l * 64 + jj] + ts * w0ts[l * 64 + jj];
            float s1 = 0.f, s2 = 0.f, s3 = 0.f;
            #pragma unroll
            for (int k4 = 0; k4 < 8; k4++) {
                float4 wv = wr[k4];
                s0 += x[kb + 4 * k4 + 0] * wv.x;
                s1 += x[kb + 4 * k4 + 1] * wv.y;
                s2 += x[kb + 4 * k4 + 2] * wv.z;
                s3 += x[kb + 4 * k4 + 3] * wv.w;
            }
            as_[jj * 256 + tid] = tanhf_((s0 + s1) + (s2 + s3));
        }
        // mv2: row-broadcast, static acc
        float acc[64];
        #pragma unroll
        for (int j4 = 0; j4 < 16; j4++) {
            float4 bv = *(const float4*)(fb1s + l * 64 + 4 * j4);
            acc[4 * j4 + 0] = bv.x; acc[4 * j4 + 1] = bv.y;
            acc[4 * j4 + 2] = bv.z; acc[4 * j4 + 3] = bv.w;
        }
        #pragma unroll 2
        for (int k = 0; k < 64; k++) {
            const float ak = as_[k * 256 + tid];
            const float4* wr = (const float4*)(w1s + (l * 64 + k) * 64);
            #pragma unroll
            for (int j4 = 0; j4 < 16; j4++) {
                float4 wv = wr[j4];
                acc[4 * j4 + 0] += ak * wv.x;
                acc[4 * j4 + 1] += ak * wv.y;
                acc[4 * j4 + 2] += ak * wv.z;
                acc[4 * j4 + 3] += ak * wv.w;
            }
        }
        #pragma unroll
        for (int jj = 0; jj < 64; jj++) as_[jj * 256 + tid] = tanhf_(acc[jj]);
        // mv3: consumed 64 cols only
        #pragma unroll
        for (int j4 = 0; j4 < 16; j4++) {
            float4 bv = *(const float4*)(fb2c + l * 64 + 4 * j4);
            acc[4 * j4 + 0] = bv.x; acc[4 * j4 + 1] = bv.y;
            acc[4 * j4 + 2] = bv.z; acc[4 * j4 + 3] = bv.w;
        }
        #pragma unroll 2
        for (int k = 0; k < 64; k++) {
            const float ak = as_[k * 256 + tid];
            const float4* wr = (const float4*)(w2s + (l * 64 + k) * 64);
            #pragma unroll
            for (int j4 = 0; j4 < 16; j4++) {
                float4 wv = wr[j4];
                acc[4 * j4 + 0] += ak * wv.x;
                acc[4 * j4 + 1] += ak * wv.y;
                acc[4 * j4 + 2] += ak * wv.z;
                acc[4 * j4 + 3] += ak * wv.w;
            }
        }
        // coupling update
        #pragma unroll
        for (int i = 0; i < 32; i++) {
            const float tsc = tanhf_(ts * ftwa[l * 32 + i]);
            const float tsh = tanhf_(ts * ftwb[l * 32 + i]);
            x[act + i] = x[act + i] * __expf(acc[i] * tsc) + acc[32 + i] * tsh;
        }
    }
    // intensity + loss contribution
    float d0 = bi0, d1 = 0.f, d2 = 0.f, d3 = 0.f;
    #pragma unroll
    for (int k4 = 0; k4 < 16; k4++) {
        float4 wv = *(const float4*)(wis + 4 * k4);
        d0 += x[4 * k4 + 0] * wv.x;
        d1 += x[4 * k4 + 1] * wv.y;
        d2 += x[4 * k4 + 2] * wv.z;
        d3 += x[4 * k4 + 3] * wv.w;
    }
    float contrib = softplusf_((d0 + d1) + (d2 + d3)) * scalef;
    #pragma unroll
    for (int off = 32; off >= 1; off >>= 1) contrib += __shfl_xor(contrib, off, 64);
    if ((tid & 63) == 0) atomicAdd(out, contrib);
}

// ---------------------------------------------------------------------------
extern "C" void kernel_launch(void* const* d_in, const int* in_sizes, int n_in,
                              void* d_out, int out_size, void* d_ws, size_t ws_size,
                              hipStream_t stream)
{
    const float* times = (const float*)d_in[0];
    const int*   marks = (const int*)  d_in[1];
    const float* mask  = (const float*)d_in[2];
    const float* u     = (const float*)d_in[3];
    const float* emb   = (const float*)d_in[4];
    const float* fW0   = (const float*)d_in[5];
    const float* fb0   = (const float*)d_in[6];
    const float* fW1   = (const float*)d_in[7];
    const float* fb1   = (const float*)d_in[8];
    const float* fW2   = (const float*)d_in[9];
    const float* fb2   = (const float*)d_in[10];
    const float* ftw   = (const float*)d_in[11];
    const float* Wi    = (const float*)d_in[12];
    const float* bi    = (const float*)d_in[13];
    const float* W_ih  = (const float*)d_in[14];
    const float* W_hh  = (const float*)d_in[15];
    const float* b_ih  = (const float*)d_in[16];
    const float* b_hh  = (const float*)d_in[17];
    float* out = (float*)d_out;

    float* wsp     = (float*)d_ws;
    float* h_carry = wsp;                   // 2097152
    float* gc      = h_carry + 2097152;     // 65536
    float* invd    = gc + 65536;            // 4
    float* parw    = invd + 4;              // 21248

    hipMemsetAsync(d_out, 0, sizeof(float), stream);

    const int PAR_SMEM = (16384 + PARW_FLOATS) * 4;   // 150528 B
    hipFuncSetAttribute((const void*)par_kernel,
                        hipFuncAttributeMaxDynamicSharedMemorySize, PAR_SMEM);

    prep_kernel<<<261, 256, 0, stream>>>(marks, mask, emb, fW0, fW1, fW2,
                                         fb0, fb1, fb2, ftw, Wi, W_ih,
                                         b_ih, b_hh, gc, parw, invd);
    seq_kernel<<<Bn, 256, 0, stream>>>(times, mask, fW0, fb0, fW1, fb1,
                                       fb2, ftw, Wi, bi, W_ih, W_hh,
                                       gc, parw, invd, h_carry, out);
    par_kernel<<<(Bn * Tn * MCn) / 256, 256, PAR_SMEM, stream>>>(
        times, mask, u, bi, invd, parw, h_carry, out);
}

// Round 4
// 992.328 us; speedup vs baseline: 3.1731x; 3.1731x over previous
//
#include <hip/hip_runtime.h>
#include <math.h>

#define Bn   256
#define Tn   128
#define HID  64
#define MCn  30

typedef __attribute__((ext_vector_type(8))) short bf16x8;
typedef __attribute__((ext_vector_type(4))) float f32x4;

// ---------------------------------------------------------------------------
// fast transcendentals (v_exp_f32 / v_rcp_f32 based)
__device__ __forceinline__ float rcp_(float x) { return __builtin_amdgcn_rcpf(x); }
__device__ __forceinline__ float tanhf_(float x) {
    float xx = fminf(fmaxf(x, -9.0f), 9.0f);
    float e  = __expf(2.0f * xx);
    return (e - 1.0f) * rcp_(e + 1.0f);
}
__device__ __forceinline__ float sigmoidf_(float x) {
    return rcp_(1.0f + __expf(-x));
}
__device__ __forceinline__ float softplusf_(float z) {
    float e = __expf(-fabsf(z));
    return fmaxf(z, 0.0f) + __logf(1.0f + e);
}
// fp32 -> bf16 (RNE)
__device__ __forceinline__ unsigned short f2b(float f) {
    union { float f; unsigned u; } v; v.f = f;
    unsigned r = v.u + 0x7FFF + ((v.u >> 16) & 1);
    return (unsigned short)(r >> 16);
}

// parv (fp32 vector block for par, 768 floats):
//   [0]   b0[l*64+m]      [128] w0t[l*64+m]   [256] b1[l*64+m]
//   [384] b2c[l*64+i] = fb2[l][act+(i&31)+64*(i>>5)]
//   [512] ftwa[l*32+i] = ftw[l][act+i]   [576] ftwb[l*32+i] = ftw[l][64+act+i]
//   [640] Wi[64]          [704] pad
// parwb (bf16 weight image, 23552 ushorts, A-operand layouts [out m][in k]):
//   [0]     w0a[l][64][40]: fW0[l][32l+k][m], k<32
//   [5120]  w1b[l][64][72]: fW1[l][k][m],     k<64
//   [14336] w2b[l][64][72]: fW2[l][k][act+(m&31)+64*(m>>5)], k<64
extern "C" __global__ __launch_bounds__(256)
void prep_kernel(const int* __restrict__ marks, const float* __restrict__ mask,
                 const float* __restrict__ emb, const float* __restrict__ fW0,
                 const float* __restrict__ fW1, const float* __restrict__ fW2,
                 const float* __restrict__ fb0, const float* __restrict__ fb1,
                 const float* __restrict__ fb2, const float* __restrict__ ftw,
                 const float* __restrict__ Wi, const float* __restrict__ W_ih,
                 const float* __restrict__ b_ih, const float* __restrict__ b_hh,
                 float* __restrict__ gc, float* __restrict__ invd,
                 float* __restrict__ seqw2, float* __restrict__ parv,
                 unsigned short* __restrict__ parwb)
{
    __shared__ float red[4];
    const int blk = blockIdx.x, tid = threadIdx.x;
    if (blk < Bn) {
        const int mark = marks[blk * Tn + 1];
        const float* er = emb + mark * HID;
        const float* wr = W_ih + tid * 65 + 1;
        float acc = b_ih[tid] + b_hh[tid];
        #pragma unroll
        for (int k = 0; k < HID; k++) acc += er[k] * wr[k];
        gc[blk * 256 + tid] = acc;
    } else if (blk == Bn) {
        float s = 0.f;
        for (int i = tid; i < Bn * Tn; i += 256) s += mask[i];
        #pragma unroll
        for (int off = 32; off >= 1; off >>= 1) s += __shfl_xor(s, off, 64);
        if ((tid & 63) == 0) red[tid >> 6] = s;
        __syncthreads();
        if (tid == 0) invd[0] = 1.0f / (red[0] + red[1] + red[2] + red[3]);
    } else if (blk == Bn + 1) {
        for (int i = tid; i < 8192; i += 256) {
            int col = i & 63, k = (i >> 6) & 63, l = i >> 12;
            int act = 32 * (1 - l);
            seqw2[i] = fW2[(l * 64 + k) * 128 + act + (col & 31) + 64 * (col >> 5)];
        }
    } else if (blk == Bn + 2) {
        if (tid < 128) {
            int l = tid >> 6, m = tid & 63;
            parv[tid]       = fb0[tid];
            parv[128 + tid] = fW0[(l * 65 + 64) * 64 + m];
            parv[256 + tid] = fb1[tid];
            int act = 32 * (1 - l);
            parv[384 + tid] = fb2[l * 128 + act + (m & 31) + 64 * (m >> 5)];
        }
        if (tid < 64) {
            int l = tid >> 5, i2 = tid & 31, act = 32 * (1 - l);
            parv[512 + tid] = ftw[l * 128 + act + i2];
            parv[576 + tid] = ftw[l * 128 + 64 + act + i2];
            parv[640 + tid] = Wi[tid];
            parv[704 + tid] = 0.f;
        }
    } else if (blk == Bn + 3) {
        for (int i = tid; i < 5120; i += 256) {
            int k = i % 40, m = (i / 40) & 63, l = i / 2560;
            float v = (k < 32) ? fW0[(l * 65 + 32 * l + k) * 64 + m] : 0.f;
            parwb[i] = f2b(v);
        }
    } else if (blk == Bn + 4) {
        for (int i = tid; i < 9216; i += 256) {
            int k = i % 72, m = (i / 72) & 63, l = i / 4608;
            float v = (k < 64) ? fW1[(l * 64 + k) * 64 + m] : 0.f;
            parwb[5120 + i] = f2b(v);
        }
    } else {
        for (int i = tid; i < 9216; i += 256) {
            int k = i % 72, m = (i / 72) & 63, l = i / 4608;
            int act = 32 * (1 - l);
            float v = (k < 64) ? fW2[(l * 64 + k) * 128 + act + (m & 31) + 64 * (m >> 5)] : 0.f;
            parwb[14336 + i] = f2b(v);
        }
    }
}

// ---------------------------------------------------------------------------
// Sequential kernel (unchanged structure from round 3): one block (4 waves)
// per batch element; mv1/mv2 replicated per wave, mv3 + LSTM split.
extern "C" __global__ __launch_bounds__(256, 1)
void seq_kernel(const float* __restrict__ times, const float* __restrict__ mask,
                const float* __restrict__ fW0, const float* __restrict__ fb0,
                const float* __restrict__ fW1, const float* __restrict__ fb1,
                const float* __restrict__ fb2, const float* __restrict__ ftw,
                const float* __restrict__ Wi, const float* __restrict__ bi,
                const float* __restrict__ W_ih, const float* __restrict__ W_hh,
                const float* __restrict__ gc, const float* __restrict__ seqw2,
                const float* __restrict__ invd,
                float* __restrict__ h_carry, float* __restrict__ out)
{
    const int tid = threadIdx.x;
    const int j = tid & 63;
    const int w = tid >> 6;
    const int b = blockIdx.x;
    const bool w0 = (w == 0);

    __shared__ __align__(16) float xl[4][64];
    __shared__ __align__(16) float al[4][64];
    __shared__ __align__(16) float al2[4][64];
    __shared__ float ssl[2][64];
    __shared__ float gl[256];

    float w0c[2][32], w0tc[2], b0c[2], w1c[2][64], b1c[2];
    float w2c[2][16], b2c[2], ftsc[2], ftsh[2];
    const int o = w * 16 + (j & 15);
    const int p = j >> 4;
    #pragma unroll
    for (int l = 0; l < 2; l++) {
        #pragma unroll
        for (int kk = 0; kk < 32; kk++)
            w0c[l][kk] = fW0[(l * 65 + 32 * l + kk) * 64 + j];
        w0tc[l] = fW0[(l * 65 + 64) * 64 + j];
        b0c[l]  = fb0[l * 64 + j];
        #pragma unroll
        for (int k = 0; k < 64; k++)
            w1c[l][k] = fW1[(l * 64 + k) * 64 + j];
        b1c[l] = fb1[l * 64 + j];
        #pragma unroll
        for (int kk = 0; kk < 16; kk++)
            w2c[l][kk] = seqw2[(l * 64 + p * 16 + kk) * 64 + o];
        const int act = 32 * (1 - l);
        b2c[l]  = fb2[l * 128 + act + (o & 31) + 64 * (o >> 5)];
        ftsc[l] = ftw[l * 128 + j];
        ftsh[l] = ftw[l * 128 + 64 + j];
    }
    float whc[64];
    {
        const float4* src = (const float4*)(W_hh + (w * 64 + j) * 64);
        #pragma unroll
        for (int k4 = 0; k4 < 16; k4++) {
            float4 v = src[k4];
            whc[4 * k4 + 0] = v.x; whc[4 * k4 + 1] = v.y;
            whc[4 * k4 + 2] = v.z; whc[4 * k4 + 3] = v.w;
        }
    }
    const float gcr  = gc[b * 256 + w * 64 + j];
    const float wih0 = W_ih[(w * 64 + j) * 65];
    const float wij  = Wi[j];
    const float bi0  = bi[0];
    const float idn  = invd[0];

    float h = 0.f, c = 0.f, nllacc = 0.f;
    float tb = times[b * Tn];
    float mk = mask[b * Tn];
    for (int t = 0; t < Tn; t++) {
        const int tn = (t < Tn - 1) ? t + 1 : t;
        const float tb_n = times[b * Tn + tn];
        const float mk_n = mask[b * Tn + tn];

        if (w0) h_carry[(b * Tn + t) * 64 + j] = h;
        float x = h;
        xl[w][j] = x;
        #pragma unroll
        for (int l = 0; l < 2; l++) {
            const int kb  = 32 * l;
            const int act = 32 * (1 - l);
            float p0 = b0c[l] + tb * w0tc[l], p1 = 0.f, p2 = 0.f, p3 = 0.f;
            {
                const float4* xv4 = (const float4*)(&xl[w][kb]);
                #pragma unroll
                for (int k4 = 0; k4 < 8; k4++) {
                    float4 xv = xv4[k4];
                    p0 += xv.x * w0c[l][4 * k4 + 0];
                    p1 += xv.y * w0c[l][4 * k4 + 1];
                    p2 += xv.z * w0c[l][4 * k4 + 2];
                    p3 += xv.w * w0c[l][4 * k4 + 3];
                }
            }
            const float a1 = tanhf_((p0 + p1) + (p2 + p3));
            al[w][j] = a1;
            p0 = b1c[l]; p1 = p2 = p3 = 0.f;
            {
                const float4* av4 = (const float4*)(&al[w][0]);
                #pragma unroll
                for (int k4 = 0; k4 < 16; k4++) {
                    float4 av = av4[k4];
                    p0 += av.x * w1c[l][4 * k4 + 0];
                    p1 += av.y * w1c[l][4 * k4 + 1];
                    p2 += av.z * w1c[l][4 * k4 + 2];
                    p3 += av.w * w1c[l][4 * k4 + 3];
                }
            }
            const float a2 = tanhf_((p0 + p1) + (p2 + p3));
            al2[w][j] = a2;
            float s0 = 0.f, s1 = 0.f, s2 = 0.f, s3 = 0.f;
            {
                const float4* av4 = (const float4*)(&al2[w][p * 16]);
                #pragma unroll
                for (int k4 = 0; k4 < 4; k4++) {
                    float4 av = av4[k4];
                    s0 += av.x * w2c[l][4 * k4 + 0];
                    s1 += av.y * w2c[l][4 * k4 + 1];
                    s2 += av.z * w2c[l][4 * k4 + 2];
                    s3 += av.w * w2c[l][4 * k4 + 3];
                }
            }
            float ss = (s0 + s1) + (s2 + s3);
            ss += __shfl_xor(ss, 16, 64);
            ss += __shfl_xor(ss, 32, 64);
            ss += b2c[l];
            if ((j & 48) == 0) ssl[l][w * 16 + j] = ss;
            __syncthreads();
            const int idx = (j - act) & 31;
            const float scl = ssl[l][idx];
            const float shf = ssl[l][32 + idx];
            const float tsc = tanhf_(tb * ftsc[l]);
            const float tsh = tanhf_(tb * ftsh[l]);
            const float xa  = x * __expf(scl * tsc) + shf * tsh;
            const bool active = (l == 0) ? (j >= 32) : (j < 32);
            x = active ? xa : x;
            xl[w][j] = x;
        }
        if (w0) out[1 + (b * Tn + t) * 64 + j] = x;
        float v = x * wij;
        #pragma unroll
        for (int off = 32; off >= 1; off >>= 1) v += __shfl_xor(v, off, 64);
        const float lam = softplusf_(v + bi0);
        if (w0) nllacc += -__logf(lam) * mk;
        float g0 = gcr + tb * wih0, g1 = 0.f, g2 = 0.f, g3 = 0.f;
        {
            const float4* hv4 = (const float4*)(&xl[w][0]);
            #pragma unroll
            for (int k4 = 0; k4 < 16; k4++) {
                float4 hv = hv4[k4];
                g0 += hv.x * whc[4 * k4 + 0];
                g1 += hv.y * whc[4 * k4 + 1];
                g2 += hv.z * whc[4 * k4 + 2];
                g3 += hv.w * whc[4 * k4 + 3];
            }
        }
        gl[w * 64 + j] = (g0 + g1) + (g2 + g3);
        __syncthreads();
        const float gi = gl[j], gf = gl[64 + j], gg = gl[128 + j], go = gl[192 + j];
        c = sigmoidf_(gf) * c + sigmoidf_(gi) * tanhf_(gg);
        h = sigmoidf_(go) * tanhf_(c);
        tb = tb_n; mk = mk_n;
    }
    if (tid == 0) atomicAdd(out, nllacc * idn);
}

// ---------------------------------------------------------------------------
// Parallel kernel, MFMA bf16. One wave = one (b,t) pair x 32 MC slots (2
// padded). Transposed GEMMs: M=out-neurons, N=samples, K=in-neurons.
// A-frags = bf16 weight images (LDS), B-frags = activation rows (LDS,
// ds_read_b128), C/D frags: col=sample, rows=4 consecutive neurons ->
// coupling state x lives in registers; a1/a2 written back as ds_write_b64.
// 76 KB LDS, 2 blocks/CU.
extern "C" __global__ __launch_bounds__(256, 2)
void par_kernel(const float* __restrict__ times, const float* __restrict__ mask,
                const float* __restrict__ u, const float* __restrict__ bi,
                const float* __restrict__ invd, const float* __restrict__ parv,
                const float4* __restrict__ parwb_f4,
                const float* __restrict__ h_carry, float* __restrict__ out)
{
    extern __shared__ char lds[];
    unsigned short* sw   = (unsigned short*)lds;            // weights [0, 47104)
    unsigned short* sact = (unsigned short*)(lds + 47104);  // [128][72] bf16
    unsigned short* sxk1 = (unsigned short*)(lds + 65536);  // [128][40] bf16
    unsigned short* sx0b = (unsigned short*)(lds + 75776);  // [4][40] bf16

    const int tid = threadIdx.x, lane = tid & 63, w = tid >> 6;
    const int quad = lane >> 4, l15 = lane & 15;

    // stage weight image
    {
        float4* d = (float4*)lds;
        for (int i = tid; i < 2944; i += 256) d[i] = parwb_f4[i];
    }
    const int q = blockIdx.x * 4 + w;
    const int t = q >> 8, b = q & 255;
    const float tb = times[b * Tn + t];
    const float* hrow = h_carry + (b * Tn + t) * 64;
    if (lane < 32) sx0b[w * 40 + lane] = f2b(hrow[lane]);
    __syncthreads();

    // per-lane sample params (sample col = nt*16 + l15 within this wave's pair)
    float tsv[2], sclf[2];
    {
        const float base = tb * (1.0f / 30.0f) * invd[0] * mask[b * Tn + t];
        #pragma unroll
        for (int nt = 0; nt < 2; nt++) {
            int mc = nt * 16 + l15;
            bool val = (mc < 30);
            tsv[nt]  = val ? u[t * MCn + mc] * tb : 0.f;
            sclf[nt] = val ? base : 0.f;
        }
    }
    // x state in registers, C-frag layout: xr[nt][mt][r] = x[sample][mt*16+quad*4+r]
    f32x4 xr[2][4];
    #pragma unroll
    for (int mt = 0; mt < 4; mt++) {
        f32x4 v = *(const f32x4*)(hrow + mt * 16 + quad * 4);
        xr[0][mt] = v; xr[1][mt] = v;
    }
    const int srow = w * 32;

    #pragma unroll
    for (int l = 0; l < 2; l++) {
        // ---- mv1: K=32 (kept half) ----
        f32x4 c1[4][2];
        {
            bf16x8 bf[2];
            if (l == 0) {
                bf16x8 bb = *(const bf16x8*)(sx0b + w * 40 + quad * 8);
                bf[0] = bb; bf[1] = bb;
            } else {
                #pragma unroll
                for (int nt = 0; nt < 2; nt++)
                    bf[nt] = *(const bf16x8*)(sxk1 + (srow + nt * 16 + l15) * 40 + quad * 8);
            }
            #pragma unroll
            for (int mt = 0; mt < 4; mt++) {
                bf16x8 af = *(const bf16x8*)(sw + l * 2560 + (mt * 16 + l15) * 40 + quad * 8);
                #pragma unroll
                for (int nt = 0; nt < 2; nt++) {
                    f32x4 z = {0.f, 0.f, 0.f, 0.f};
                    c1[mt][nt] = __builtin_amdgcn_mfma_f32_16x16x32_bf16(af, bf[nt], z, 0, 0, 0);
                }
            }
        }
        // a1 = tanh(c1 + b0 + ts*w0t) -> sact
        #pragma unroll
        for (int mt = 0; mt < 4; mt++) {
            f32x4 b0r = *(const f32x4*)(parv + 0   + l * 64 + mt * 16 + quad * 4);
            f32x4 w0r = *(const f32x4*)(parv + 128 + l * 64 + mt * 16 + quad * 4);
            #pragma unroll
            for (int nt = 0; nt < 2; nt++) {
                float v0 = tanhf_(c1[mt][nt][0] + b0r[0] + tsv[nt] * w0r[0]);
                float v1 = tanhf_(c1[mt][nt][1] + b0r[1] + tsv[nt] * w0r[1]);
                float v2 = tanhf_(c1[mt][nt][2] + b0r[2] + tsv[nt] * w0r[2]);
                float v3 = tanhf_(c1[mt][nt][3] + b0r[3] + tsv[nt] * w0r[3]);
                uint2 pk;
                pk.x = ((unsigned)f2b(v1) << 16) | f2b(v0);
                pk.y = ((unsigned)f2b(v3) << 16) | f2b(v2);
                *(uint2*)(sact + (srow + nt * 16 + l15) * 72 + mt * 16 + quad * 4) = pk;
            }
        }
        // ---- mv2: K=64 ----
        f32x4 cc[4][2];
        #pragma unroll
        for (int mt = 0; mt < 4; mt++)
            #pragma unroll
            for (int nt = 0; nt < 2; nt++) cc[mt][nt] = (f32x4){0.f, 0.f, 0.f, 0.f};
        #pragma unroll
        for (int kt = 0; kt < 2; kt++) {
            bf16x8 bf[2];
            #pragma unroll
            for (int nt = 0; nt < 2; nt++)
                bf[nt] = *(const bf16x8*)(sact + (srow + nt * 16 + l15) * 72 + kt * 32 + quad * 8);
            #pragma unroll
            for (int mt = 0; mt < 4; mt++) {
                bf16x8 af = *(const bf16x8*)(sw + 5120 + l * 4608 + (mt * 16 + l15) * 72 + kt * 32 + quad * 8);
                #pragma unroll
                for (int nt = 0; nt < 2; nt++)
                    cc[mt][nt] = __builtin_amdgcn_mfma_f32_16x16x32_bf16(af, bf[nt], cc[mt][nt], 0, 0, 0);
            }
        }
        // a2 = tanh(cc + b1) -> sact (in-order DS: all mv2 reads precede)
        #pragma unroll
        for (int mt = 0; mt < 4; mt++) {
            f32x4 b1r = *(const f32x4*)(parv + 256 + l * 64 + mt * 16 + quad * 4);
            #pragma unroll
            for (int nt = 0; nt < 2; nt++) {
                float v0 = tanhf_(cc[mt][nt][0] + b1r[0]);
                float v1 = tanhf_(cc[mt][nt][1] + b1r[1]);
                float v2 = tanhf_(cc[mt][nt][2] + b1r[2]);
                float v3 = tanhf_(cc[mt][nt][3] + b1r[3]);
                uint2 pk;
                pk.x = ((unsigned)f2b(v1) << 16) | f2b(v0);
                pk.y = ((unsigned)f2b(v3) << 16) | f2b(v2);
                *(uint2*)(sact + (srow + nt * 16 + l15) * 72 + mt * 16 + quad * 4) = pk;
            }
        }
        // ---- mv3: K=64, 64 consumed outputs (scale rows 0..31, shift 32..63) ----
        f32x4 ssf[4][2];
        #pragma unroll
        for (int mt = 0; mt < 4; mt++)
            #pragma unroll
            for (int nt = 0; nt < 2; nt++) ssf[mt][nt] = (f32x4){0.f, 0.f, 0.f, 0.f};
        #pragma unroll
        for (int kt = 0; kt < 2; kt++) {
            bf16x8 bf[2];
            #pragma unroll
            for (int nt = 0; nt < 2; nt++)
                bf[nt] = *(const bf16x8*)(sact + (srow + nt * 16 + l15) * 72 + kt * 32 + quad * 8);
            #pragma unroll
            for (int mt = 0; mt < 4; mt++) {
                bf16x8 af = *(const bf16x8*)(sw + 14336 + l * 4608 + (mt * 16 + l15) * 72 + kt * 32 + quad * 8);
                #pragma unroll
                for (int nt = 0; nt < 2; nt++)
                    ssf[mt][nt] = __builtin_amdgcn_mfma_f32_16x16x32_bf16(af, bf[nt], ssf[mt][nt], 0, 0, 0);
            }
        }
        // coupling update in registers
        #pragma unroll
        for (int mt2 = 0; mt2 < 2; mt2++) {
            f32x4 b2s = *(const f32x4*)(parv + 384 + l * 64 +      mt2 * 16 + quad * 4);
            f32x4 b2h = *(const f32x4*)(parv + 384 + l * 64 + 32 + mt2 * 16 + quad * 4);
            f32x4 fa  = *(const f32x4*)(parv + 512 + l * 32 + mt2 * 16 + quad * 4);
            f32x4 fb  = *(const f32x4*)(parv + 576 + l * 32 + mt2 * 16 + quad * 4);
            const int xm = (l == 0) ? (mt2 + 2) : mt2;
            #pragma unroll
            for (int nt = 0; nt < 2; nt++) {
                #pragma unroll
                for (int r = 0; r < 4; r++) {
                    float sc  = ssf[mt2][nt][r] + b2s[r];
                    float sh  = ssf[mt2 + 2][nt][r] + b2h[r];
                    float tsc = tanhf_(tsv[nt] * fa[r]);
                    float tsh = tanhf_(tsv[nt] * fb[r]);
                    float xv  = xr[nt][xm][r];
                    xr[nt][xm][r] = xv * __expf(sc * tsc) + sh * tsh;
                }
                if (l == 0) {
                    uint2 pk;
                    pk.x = ((unsigned)f2b(xr[nt][xm][1]) << 16) | f2b(xr[nt][xm][0]);
                    pk.y = ((unsigned)f2b(xr[nt][xm][3]) << 16) | f2b(xr[nt][xm][2]);
                    *(uint2*)(sxk1 + (srow + nt * 16 + l15) * 40 + mt2 * 16 + quad * 4) = pk;
                }
            }
        }
    }
    // ---- intensity + loss contribution ----
    float contrib = 0.f;
    const float bi0 = bi[0];
    #pragma unroll
    for (int nt = 0; nt < 2; nt++) {
        float d0 = 0.f, d1 = 0.f;
        #pragma unroll
        for (int mt = 0; mt < 4; mt++) {
            f32x4 wi4 = *(const f32x4*)(parv + 640 + mt * 16 + quad * 4);
            d0 += xr[nt][mt][0] * wi4[0] + xr[nt][mt][2] * wi4[2];
            d1 += xr[nt][mt][1] * wi4[1] + xr[nt][mt][3] * wi4[3];
        }
        float d = d0 + d1;
        d += __shfl_xor(d, 16, 64);
        d += __shfl_xor(d, 32, 64);
        contrib += softplusf_(d + bi0) * sclf[nt];
    }
    if (quad != 0) contrib = 0.f;
    #pragma unroll
    for (int off = 1; off <= 32; off <<= 1) contrib += __shfl_xor(contrib, off, 64);
    if (lane == 0) atomicAdd(out, contrib);
}

// ---------------------------------------------------------------------------
extern "C" void kernel_launch(void* const* d_in, const int* in_sizes, int n_in,
                              void* d_out, int out_size, void* d_ws, size_t ws_size,
                              hipStream_t stream)
{
    const float* times = (const float*)d_in[0];
    const int*   marks = (const int*)  d_in[1];
    const float* mask  = (const float*)d_in[2];
    const float* u     = (const float*)d_in[3];
    const float* emb   = (const float*)d_in[4];
    const float* fW0   = (const float*)d_in[5];
    const float* fb0   = (const float*)d_in[6];
    const float* fW1   = (const float*)d_in[7];
    const float* fb1   = (const float*)d_in[8];
    const float* fW2   = (const float*)d_in[9];
    const float* fb2   = (const float*)d_in[10];
    const float* ftw   = (const float*)d_in[11];
    const float* Wi    = (const float*)d_in[12];
    const float* bi    = (const float*)d_in[13];
    const float* W_ih  = (const float*)d_in[14];
    const float* W_hh  = (const float*)d_in[15];
    const float* b_ih  = (const float*)d_in[16];
    const float* b_hh  = (const float*)d_in[17];
    float* out = (float*)d_out;

    float* wsp     = (float*)d_ws;
    float* h_carry = wsp;                   // 2,097,152 floats
    float* gc      = h_carry + 2097152;     // 65,536
    float* invd    = gc + 65536;            // 4
    float* seqw2   = invd + 4;              // 8,192
    float* parv    = seqw2 + 8192;          // 768
    unsigned short* parwb = (unsigned short*)(parv + 768);   // 23,552 ushorts (16B-aligned)

    hipMemsetAsync(d_out, 0, sizeof(float), stream);

    const int PAR_SMEM = 76096;
    hipFuncSetAttribute((const void*)par_kernel,
                        hipFuncAttributeMaxDynamicSharedMemorySize, PAR_SMEM);

    prep_kernel<<<262, 256, 0, stream>>>(marks, mask, emb, fW0, fW1, fW2,
                                         fb0, fb1, fb2, ftw, Wi, W_ih,
                                         b_ih, b_hh, gc, invd, seqw2, parv, parwb);
    seq_kernel<<<Bn, 256, 0, stream>>>(times, mask, fW0, fb0, fW1, fb1,
                                       fb2, ftw, Wi, bi, W_ih, W_hh,
                                       gc, seqw2, invd, h_carry, out);
    par_kernel<<<(Bn * Tn) / 4, 256, PAR_SMEM, stream>>>(
        times, mask, u, bi, invd, parv, (const float4*)parwb, h_carry, out);
}